// Round 1
// baseline (269.839 us; speedup 1.0000x reference)
//
#include <hip/hip_runtime.h>

typedef __attribute__((ext_vector_type(8))) __bf16 bf16x8;
typedef __attribute__((ext_vector_type(4))) float f32x4;

#define N_SAMP 256
#define DIM    2048
#define NCENT  32000
#define INV_T  14.285714285714285714f   // 1 / 0.07

// ---------------- kernel 1: row-normalize feats, emit bf16 ----------------
__global__ __launch_bounds__(256) void norm_kernel(const float* __restrict__ feats,
                                                   __bf16* __restrict__ fnorm) {
    int row = blockIdx.x;
    int tid = threadIdx.x;
    const float* src = feats + (size_t)row * DIM;
    float4 v0 = reinterpret_cast<const float4*>(src)[2 * tid];
    float4 v1 = reinterpret_cast<const float4*>(src)[2 * tid + 1];
    float ss = v0.x * v0.x + v0.y * v0.y + v0.z * v0.z + v0.w * v0.w
             + v1.x * v1.x + v1.y * v1.y + v1.z * v1.z + v1.w * v1.w;
    #pragma unroll
    for (int off = 1; off < 64; off <<= 1) ss += __shfl_xor(ss, off, 64);
    __shared__ float wsum[4];
    if ((tid & 63) == 0) wsum[tid >> 6] = ss;
    __syncthreads();
    float inv = 1.0f / sqrtf(wsum[0] + wsum[1] + wsum[2] + wsum[3]);
    bf16x8 o;
    o[0] = (__bf16)(v0.x * inv); o[1] = (__bf16)(v0.y * inv);
    o[2] = (__bf16)(v0.z * inv); o[3] = (__bf16)(v0.w * inv);
    o[4] = (__bf16)(v1.x * inv); o[5] = (__bf16)(v1.y * inv);
    o[6] = (__bf16)(v1.z * inv); o[7] = (__bf16)(v1.w * inv);
    *reinterpret_cast<bf16x8*>(fnorm + (size_t)row * DIM + tid * 8) = o;
}

// ------------- kernel 2: fused GEMM (256 x 64 tile) + masked reduce -------------
// block = 4 waves; wave w owns sample rows [w*64, w*64+64), block owns 64 centers.
__global__ __launch_bounds__(256, 2) void sims_kernel(
    const __bf16* __restrict__ fnorm, const float* __restrict__ centers,
    const int* __restrict__ labels, const int* __restrict__ camids,
    float* __restrict__ d_intra, float* __restrict__ d_inter, float* __restrict__ d_own)
{
    __shared__ int s_lab[N_SAMP], s_cam[N_SAMP];
    int tid = threadIdx.x;
    s_lab[tid] = labels[tid];
    s_cam[tid] = camids[tid];
    __syncthreads();

    const int wave  = tid >> 6;
    const int lane  = tid & 63;
    const int l15   = lane & 15;
    const int lhi   = lane >> 4;
    const int mbase = wave * 64;
    const int cbase = blockIdx.x * 64;

    f32x4 acc[4][4] = {};

    const __bf16* abase = fnorm   + (size_t)(mbase + l15) * DIM + lhi * 8;
    const float*  bbase = centers + (size_t)(cbase + l15) * DIM + lhi * 8;

    #pragma unroll 2
    for (int k0 = 0; k0 < DIM; k0 += 32) {
        bf16x8 afrag[4], bfrag[4];
        #pragma unroll
        for (int mi = 0; mi < 4; ++mi)
            afrag[mi] = *reinterpret_cast<const bf16x8*>(abase + (size_t)mi * 16 * DIM + k0);
        #pragma unroll
        for (int ni = 0; ni < 4; ++ni) {
            const float* p = bbase + (size_t)ni * 16 * DIM + k0;
            float4 x = *reinterpret_cast<const float4*>(p);
            float4 y = *reinterpret_cast<const float4*>(p + 4);
            bf16x8 b;
            b[0] = (__bf16)x.x; b[1] = (__bf16)x.y; b[2] = (__bf16)x.z; b[3] = (__bf16)x.w;
            b[4] = (__bf16)y.x; b[5] = (__bf16)y.y; b[6] = (__bf16)y.z; b[7] = (__bf16)y.w;
            bfrag[ni] = b;
        }
        #pragma unroll
        for (int mi = 0; mi < 4; ++mi)
            #pragma unroll
            for (int ni = 0; ni < 4; ++ni)
                acc[mi][ni] = __builtin_amdgcn_mfma_f32_16x16x32_bf16(
                    afrag[mi], bfrag[ni], acc[mi][ni], 0, 0, 0);
    }

    // epilogue: D element (mi,ni,r) -> sample row mbase+mi*16+lhi*4+r, center cbase+ni*16+l15
    #pragma unroll
    for (int mi = 0; mi < 4; ++mi) {
        #pragma unroll
        for (int r = 0; r < 4; ++r) {
            int i   = mbase + mi * 16 + lhi * 4 + r;
            int lab = s_lab[i], cam = s_cam[i];
            int oidx = lab * 8 + cam;
            bool intra_ok = ((l15 & 7) == cam);   // c % 8 uniform over ni
            float p_intra = 0.f, p_inter = 0.f;
            #pragma unroll
            for (int ni = 0; ni < 4; ++ni) {
                int c = cbase + ni * 16 + l15;
                float s = acc[mi][ni][r] * INV_T;
                float e = __expf(s);
                if (intra_ok) p_intra += e;
                bool own_lab = ((c >> 3) == lab);
                bool hard = (!own_lab) && (c < ((c < lab * 8) ? 50 : 58));
                if (own_lab || hard) p_inter += e;
                if (c == oidx) d_own[i] = s;
            }
            #pragma unroll
            for (int off = 1; off < 16; off <<= 1) {
                p_intra += __shfl_xor(p_intra, off, 64);
                p_inter += __shfl_xor(p_inter, off, 64);
            }
            if (l15 == 0) {
                atomicAdd(&d_intra[i], p_intra);
                atomicAdd(&d_inter[i], p_inter);
            }
        }
    }
}

// ---------------- kernel 3: finalize (segment means + output) ----------------
__global__ __launch_bounds__(256) void finalize_kernel(
    const float* __restrict__ d_intra, const float* __restrict__ d_inter,
    const float* __restrict__ d_own,
    const int* __restrict__ labels, const int* __restrict__ camids,
    float* __restrict__ out, int out_size)
{
    __shared__ int s_lab[N_SAMP], s_cam[N_SAMP];
    __shared__ float wsum[8];
    int tid = threadIdx.x;
    s_lab[tid] = labels[tid];
    s_cam[tid] = camids[tid];
    __syncthreads();
    int myl = s_lab[tid], myc = s_cam[tid];
    int nl = 0, nc = 0;
    for (int j = 0; j < N_SAMP; ++j) {
        nl += (s_lab[j] == myl);
        nc += (s_cam[j] == myc);
    }
    float own = d_own[tid];
    float li = own - logf(d_intra[tid]);
    float lj = own - logf(d_inter[tid]);
    float a = li / (float)nc;   // sum_i loss_i / n_cam == sum over cams of per-cam mean
    float b = lj / (float)nl;
    #pragma unroll
    for (int off = 1; off < 64; off <<= 1) {
        a += __shfl_xor(a, off, 64);
        b += __shfl_xor(b, off, 64);
    }
    if ((tid & 63) == 0) { wsum[tid >> 6] = a; wsum[4 + (tid >> 6)] = b; }
    __syncthreads();
    if (tid == 0) {
        float sa = wsum[0] + wsum[1] + wsum[2] + wsum[3];
        float sb = wsum[4] + wsum[5] + wsum[6] + wsum[7];
        out[0] = -sa;
        if (out_size > 1) out[1] = -0.5f * sb;   // LAMDA = 0.5
    }
}

extern "C" void kernel_launch(void* const* d_in, const int* in_sizes, int n_in,
                              void* d_out, int out_size, void* d_ws, size_t ws_size,
                              hipStream_t stream) {
    const float* feats   = (const float*)d_in[0];
    const float* centers = (const float*)d_in[1];
    const int*   labels  = (const int*)d_in[2];
    const int*   camids  = (const int*)d_in[3];
    float* out = (float*)d_out;

    __bf16* fnorm  = (__bf16*)d_ws;
    float* d_intra = (float*)((char*)d_ws + (size_t)N_SAMP * DIM * sizeof(__bf16));
    float* d_inter = d_intra + N_SAMP;
    float* d_own   = d_intra + 2 * N_SAMP;

    hipMemsetAsync(d_intra, 0, 2 * N_SAMP * sizeof(float), stream);
    norm_kernel<<<N_SAMP, 256, 0, stream>>>(feats, fnorm);
    sims_kernel<<<NCENT / 64, 256, 0, stream>>>(fnorm, centers, labels, camids,
                                                d_intra, d_inter, d_own);
    finalize_kernel<<<1, 256, 0, stream>>>(d_intra, d_inter, d_own, labels, camids,
                                           out, out_size);
}